// Round 3
// baseline (2179.996 us; speedup 1.0000x reference)
//
#include <hip/hip_runtime.h>

// Round 3: f32 in/out confirmed. bf16x3 emulated-f32 MFMA GEMMs (Ah*Wh + Al*Wh + Ah*Wl),
// fragment-major pre-split weights, fused score epilogue on the edge GEMM, f32 edge math.
// m = (h[src]+efeat)@W1+b1 = eW1[e] + hW1[src] (b1 folded into hW1).

typedef unsigned short u16;
typedef short bf16x8 __attribute__((ext_vector_type(8)));
typedef float f32x4 __attribute__((ext_vector_type(4)));
typedef _Float16 f16x2 __attribute__((ext_vector_type(2)));

#define NEG_SLOPE 0.22916666666666666f

__device__ inline float bf2f(u16 h) { return __uint_as_float(((unsigned)h) << 16); }
__device__ inline u16 f2bf(float f) {
  unsigned u = __float_as_uint(f);
  u += 0x7fffu + ((u >> 16) & 1u);   // RNE
  return (u16)(u >> 16);
}
__device__ inline unsigned f2ord(float f) {
  unsigned u = __float_as_uint(f);
  return (u & 0x80000000u) ? ~u : (u | 0x80000000u);
}
__device__ inline float ord2f(unsigned u) {
  return __uint_as_float((u & 0x80000000u) ? (u & 0x7fffffffu) : ~u);
}

// ---------------------------------------------------------------------------
// Pre-split 6 weight matrices into MFMA-fragment-major bf16 hi/lo buffers.
// Frag layout per matrix (32768 u16): [((t*4+kc)*2+hl)*512 + lane*8 + j]
// holds W[k=kc*32+(lane>>4)*8+j][n=t*16+(lane&15)]  (i.e. B-frag for 16x16x32).
// ---------------------------------------------------------------------------
__global__ __launch_bounds__(256)
void prep_weights(const float* w0, const float* w1, const float* w2,
                  const float* w3, const float* w4, const float* w5,
                  const float* c0, const float* c1, const float* c2,
                  const float* c3, const float* c4, const float* c5,
                  u16* __restrict__ wf, float* __restrict__ bf) {
  int b = blockIdx.x, tid = threadIdx.x;
  const float* W = b == 0 ? w0 : b == 1 ? w1 : b == 2 ? w2 : b == 3 ? w3 : b == 4 ? w4 : w5;
  const float* C = b == 0 ? c0 : b == 1 ? c1 : b == 2 ? c2 : b == 3 ? c3 : b == 4 ? c4 : c5;
  u16* out = wf + (size_t)b * 32768;
  for (int q = 0; q < 64; ++q) {
    int fi = tid * 64 + q;
    int t = fi >> 11, kc = (fi >> 9) & 3, lane = (fi >> 3) & 63, j = fi & 7;
    int k = kc * 32 + (lane >> 4) * 8 + j;
    int n = t * 16 + (lane & 15);
    float w = W[k * 128 + n];
    u16 hi = f2bf(w);
    u16 lo = f2bf(w - bf2f(hi));
    int base = ((t * 4 + kc) * 2) * 512 + lane * 8 + j;
    out[base] = hi;
    out[base + 512] = lo;
  }
  if (tid < 128) bf[b * 128 + tid] = C[tid];
}

// ---------------------------------------------------------------------------
// C_f32[M,128] = A_f32[M,128] @ W (+bias), bf16x3. 256thr/4 waves, 64 rows/blk.
// ---------------------------------------------------------------------------
__global__ __launch_bounds__(256)
void gemm_n(const float* __restrict__ A, const u16* __restrict__ wf,
            const float* __restrict__ bias, float* __restrict__ C, int M) {
  __shared__ u16 ah[64 * 136];
  __shared__ u16 al[64 * 136];
  const int tid = threadIdx.x;
  const long long rowBase = (long long)blockIdx.x * 64;
  #pragma unroll
  for (int it = 0; it < 8; ++it) {
    int idx = it * 256 + tid;            // 0..2047
    int row = idx >> 5, c4 = idx & 31;
    long long gr = rowBase + row;
    float4 v = make_float4(0.f, 0.f, 0.f, 0.f);
    if (gr < M) v = ((const float4*)A)[gr * 32 + c4];
    u16 hb[4] = {f2bf(v.x), f2bf(v.y), f2bf(v.z), f2bf(v.w)};
    u16 lb[4] = {f2bf(v.x - bf2f(hb[0])), f2bf(v.y - bf2f(hb[1])),
                 f2bf(v.z - bf2f(hb[2])), f2bf(v.w - bf2f(hb[3]))};
    *(uint2*)&ah[row * 136 + c4 * 4] = *(uint2*)hb;
    *(uint2*)&al[row * 136 + c4 * 4] = *(uint2*)lb;
  }
  __syncthreads();
  const int wid = tid >> 6, lane = tid & 63, lrow = lane & 15, lk = lane >> 4;
  bf16x8 af[4], alf[4];
  #pragma unroll
  for (int kc = 0; kc < 4; ++kc) {
    af[kc]  = *(const bf16x8*)&ah[(wid * 16 + lrow) * 136 + kc * 32 + lk * 8];
    alf[kc] = *(const bf16x8*)&al[(wid * 16 + lrow) * 136 + kc * 32 + lk * 8];
  }
  f32x4 acc[8];
  #pragma unroll
  for (int t = 0; t < 8; ++t) acc[t] = (f32x4){0.f, 0.f, 0.f, 0.f};
  #pragma unroll
  for (int t = 0; t < 8; ++t) {
    #pragma unroll
    for (int kc = 0; kc < 4; ++kc) {
      bf16x8 bh = *(const bf16x8*)&wf[((t * 4 + kc) * 2) * 512 + lane * 8];
      bf16x8 bl = *(const bf16x8*)&wf[((t * 4 + kc) * 2 + 1) * 512 + lane * 8];
      acc[t] = __builtin_amdgcn_mfma_f32_16x16x32_bf16(af[kc],  bh, acc[t], 0, 0, 0);
      acc[t] = __builtin_amdgcn_mfma_f32_16x16x32_bf16(alf[kc], bh, acc[t], 0, 0, 0);
      acc[t] = __builtin_amdgcn_mfma_f32_16x16x32_bf16(af[kc],  bl, acc[t], 0, 0, 0);
    }
  }
  #pragma unroll
  for (int t = 0; t < 8; ++t) {
    int col = t * 16 + lrow;
    float bv = bias[col];
    #pragma unroll
    for (int r = 0; r < 4; ++r) {
      long long row = rowBase + wid * 16 + lk * 4 + r;
      if (row < M) C[row * 128 + col] = acc[t][r] + bv;
    }
  }
}

// ---------------------------------------------------------------------------
// Edge GEMM over rows e in [e0,e1): eW1 = edgef@W1 via bf16x3; epilogue adds
// hW1[src] -> m (f16, chunk-local), and (DO_SCORE) score=<h[dst],m> in f32
// + atomicMax smax. msh (f32) aliases the A-staging LDS after a barrier.
// ---------------------------------------------------------------------------
template<int DO_SCORE>
__global__ __launch_bounds__(256)
void gemm_e(const float* __restrict__ A, const u16* __restrict__ wf,
            const float* __restrict__ hW1, const float* __restrict__ hvec,
            const int* __restrict__ src, const int* __restrict__ dst,
            u16* __restrict__ mout, float* __restrict__ score,
            unsigned* __restrict__ smax, long long e0, long long e1) {
  __shared__ __align__(16) char smem[34816];
  u16* ah = (u16*)smem;
  u16* al = (u16*)(smem + 17408);
  float* msh = (float*)smem;             // aliases ah/al after barrier
  const int tid = threadIdx.x;
  const long long rowBase = e0 + (long long)blockIdx.x * 64;
  #pragma unroll
  for (int it = 0; it < 8; ++it) {
    int idx = it * 256 + tid;
    int row = idx >> 5, c4 = idx & 31;
    long long gr = rowBase + row;
    float4 v = make_float4(0.f, 0.f, 0.f, 0.f);
    if (gr < e1) v = ((const float4*)A)[gr * 32 + c4];
    u16 hb[4] = {f2bf(v.x), f2bf(v.y), f2bf(v.z), f2bf(v.w)};
    u16 lb[4] = {f2bf(v.x - bf2f(hb[0])), f2bf(v.y - bf2f(hb[1])),
                 f2bf(v.z - bf2f(hb[2])), f2bf(v.w - bf2f(hb[3]))};
    *(uint2*)&ah[row * 136 + c4 * 4] = *(uint2*)hb;
    *(uint2*)&al[row * 136 + c4 * 4] = *(uint2*)lb;
  }
  __syncthreads();
  const int wid = tid >> 6, lane = tid & 63, lrow = lane & 15, lk = lane >> 4;
  bf16x8 af[4], alf[4];
  #pragma unroll
  for (int kc = 0; kc < 4; ++kc) {
    af[kc]  = *(const bf16x8*)&ah[(wid * 16 + lrow) * 136 + kc * 32 + lk * 8];
    alf[kc] = *(const bf16x8*)&al[(wid * 16 + lrow) * 136 + kc * 32 + lk * 8];
  }
  f32x4 acc[8];
  #pragma unroll
  for (int t = 0; t < 8; ++t) acc[t] = (f32x4){0.f, 0.f, 0.f, 0.f};
  #pragma unroll
  for (int t = 0; t < 8; ++t) {
    #pragma unroll
    for (int kc = 0; kc < 4; ++kc) {
      bf16x8 bh = *(const bf16x8*)&wf[((t * 4 + kc) * 2) * 512 + lane * 8];
      bf16x8 bl = *(const bf16x8*)&wf[((t * 4 + kc) * 2 + 1) * 512 + lane * 8];
      acc[t] = __builtin_amdgcn_mfma_f32_16x16x32_bf16(af[kc],  bh, acc[t], 0, 0, 0);
      acc[t] = __builtin_amdgcn_mfma_f32_16x16x32_bf16(alf[kc], bh, acc[t], 0, 0, 0);
      acc[t] = __builtin_amdgcn_mfma_f32_16x16x32_bf16(af[kc],  bl, acc[t], 0, 0, 0);
    }
  }
  __syncthreads();   // all waves done reading ah/al before msh overwrite
  #pragma unroll
  for (int t = 0; t < 8; ++t)
    #pragma unroll
    for (int r = 0; r < 4; ++r)
      msh[(wid * 16 + lk * 4 + r) * 132 + t * 16 + lrow] = acc[t][r];
  __syncthreads();

  const int r = tid >> 2, p = tid & 3;
  const long long e = rowBase + r;
  float sc = 0.f;
  int d = 0;
  if (e < e1) {
    int s = src[e];
    d = dst[e];
    const float* hw = hW1 + (size_t)s * 128 + p * 32;
    const float* hd = hvec + (size_t)d * 128 + p * 32;
    _Float16 mb[32];
    #pragma unroll
    for (int i = 0; i < 32; i += 4) {
      float4 a = *(const float4*)&msh[r * 132 + p * 32 + i];
      float4 b = *(const float4*)&hw[i];
      float m0 = a.x + b.x, m1 = a.y + b.y, m2 = a.z + b.z, m3 = a.w + b.w;
      mb[i] = (_Float16)m0; mb[i + 1] = (_Float16)m1;
      mb[i + 2] = (_Float16)m2; mb[i + 3] = (_Float16)m3;
      if (DO_SCORE) {
        float4 hh = *(const float4*)&hd[i];
        sc += m0 * hh.x + m1 * hh.y + m2 * hh.z + m3 * hh.w;
      }
    }
    u16* mrow = mout + (size_t)(e - e0) * 128 + p * 32;
    #pragma unroll
    for (int i = 0; i < 4; ++i)
      *(uint4*)&mrow[i * 8] = ((uint4*)mb)[i];
  }
  if (DO_SCORE) {
    sc += __shfl_xor(sc, 1);
    sc += __shfl_xor(sc, 2);
    if (p == 0 && e < e1) {
      score[e] = sc;
      atomicMax(&smax[d], f2ord(sc));
    }
  }
}

// ---------------------------------------------------------------------------
// Pass 2: w = exp(score - smax[dst]); denom[dst]+=w; wsum[dst]+=w*m (f32 atomics)
// ---------------------------------------------------------------------------
__global__ __launch_bounds__(256)
void edge_accum(const u16* __restrict__ m, const float* __restrict__ score,
                const unsigned* __restrict__ smax, const int* __restrict__ dst,
                float* __restrict__ denom, float* __restrict__ wsum,
                long long e0, long long e1) {
  const int lane = threadIdx.x & 63;
  const long long w0 = ((long long)blockIdx.x * blockDim.x + threadIdx.x) >> 6;
  const long long nw = ((long long)gridDim.x * blockDim.x) >> 6;
  for (long long e = e0 + w0; e < e1; e += nw) {
    int d = dst[e];
    float w = __expf(score[e] - ord2f(smax[d]));
    f16x2 mv = *(const f16x2*)&m[(size_t)(e - e0) * 128 + 2 * lane];
    size_t base = (size_t)d * 128 + 2 * lane;
    atomicAdd(&wsum[base],     w * (float)mv[0]);
    atomicAdd(&wsum[base + 1], w * (float)mv[1]);
    if (lane == 0) atomicAdd(&denom[d], w);
  }
}

// ---------------------------------------------------------------------------
// x = (denom>0 ? y2 + wsum/denom : y3); leaky-relu; f32 out.
// ---------------------------------------------------------------------------
__global__ __launch_bounds__(256)
void finalize_k(const float* __restrict__ y2, const float* __restrict__ y3,
                const float* __restrict__ wsum, const float* __restrict__ denom,
                float* __restrict__ out, int N) {
  long long gid = (long long)blockIdx.x * 256 + threadIdx.x;  // over N*64
  if (gid >= (long long)N * 64) return;
  int n = (int)(gid >> 6);
  size_t base = (size_t)gid * 2;
  float den = denom[n];
  float a, b;
  if (den > 0.f) {
    float inv = 1.f / den;
    a = y2[base]     + wsum[base]     * inv;
    b = y2[base + 1] + wsum[base + 1] * inv;
  } else {
    a = y3[base];
    b = y3[base + 1];
  }
  a = a >= 0.f ? a : a * NEG_SLOPE;
  b = b >= 0.f ? b : b * NEG_SLOPE;
  *(float2*)&out[base] = make_float2(a, b);
}

extern "C" void kernel_launch(void* const* d_in, const int* in_sizes, int n_in,
                              void* d_out, int out_size, void* d_ws, size_t ws_size,
                              hipStream_t stream) {
  const int D = 128;
  const int N = in_sizes[0] / D;
  const int E = in_sizes[1] / D;

  const float* node  = (const float*)d_in[0];
  const float* edgef = (const float*)d_in[1];
  const int* src = (const int*)d_in[2];
  const int* dst = (const int*)d_in[3];

  // workspace carve (all offsets 256B-aligned)
  char* p = (char*)d_ws;
  u16*   wfrag = (u16*)p;    p += (size_t)6 * 32768 * 2;
  float* biasf = (float*)p;  p += 4096;
  float* hW1   = (float*)p;  p += (size_t)N * 512;
  float* y2    = (float*)p;  p += (size_t)N * 512;
  float* y3    = (float*)p;  p += (size_t)N * 512;
  float* h1    = (float*)p;  p += (size_t)N * 512;
  float* score = (float*)p;  p += (size_t)E * 4;
  unsigned* smax = (unsigned*)p; p += (size_t)N * 4;   // zero region start
  float* denom = (float*)p;      p += (size_t)N * 4;
  float* wsum  = (float*)p;      p += (size_t)N * 512;
  size_t zbytes = (size_t)N * (2 + D) * 4;
  u16* mbuf = (u16*)p;            // chunked m (f16), takes remaining space
  size_t fixed = (size_t)(p - (char*)d_ws);

  long long chunkE = E;
  if (ws_size > fixed) {
    long long cap = (long long)((ws_size - fixed) / 256) & ~63LL;
    if (cap < 64) cap = 64;
    if (cap < chunkE) chunkE = cap;
  }
  int nchunk = (int)((E + chunkE - 1) / chunkE);

  prep_weights<<<6, 256, 0, stream>>>(
      (const float*)d_in[4],  (const float*)d_in[6],  (const float*)d_in[8],
      (const float*)d_in[10], (const float*)d_in[12], (const float*)d_in[14],
      (const float*)d_in[5],  (const float*)d_in[7],  (const float*)d_in[9],
      (const float*)d_in[11], (const float*)d_in[13], (const float*)d_in[15],
      wfrag, biasf);

  const int gN = (N + 63) / 64;
  const int finB = (N * 64 + 255) / 256;

  for (int l = 0; l < 2; ++l) {
    const float* h = (l == 0) ? node : h1;
    float* hout = (l == 0) ? h1 : (float*)d_out;
    const u16* wf1 = wfrag + (size_t)(l * 3 + 0) * 32768;
    const u16* wf2 = wfrag + (size_t)(l * 3 + 1) * 32768;
    const u16* wf3 = wfrag + (size_t)(l * 3 + 2) * 32768;
    const float* b1 = biasf + (l * 3 + 0) * 128;
    const float* b2 = biasf + (l * 3 + 1) * 128;
    const float* b3 = biasf + (l * 3 + 2) * 128;

    gemm_n<<<gN, 256, 0, stream>>>(h, wf1, b1, hW1, N);
    gemm_n<<<gN, 256, 0, stream>>>(h, wf2, b2, y2, N);
    gemm_n<<<gN, 256, 0, stream>>>(h, wf3, b3, y3, N);
    hipMemsetAsync(smax, 0, zbytes, stream);   // smax ord-init 0 < any real; denom/wsum = 0

    for (int c = 0; c < nchunk; ++c) {
      long long e0 = (long long)c * chunkE;
      long long e1 = e0 + chunkE < E ? e0 + chunkE : E;
      int blocks = (int)((e1 - e0 + 63) / 64);
      gemm_e<1><<<blocks, 256, 0, stream>>>(edgef, wf1, hW1, h, src, dst,
                                            mbuf, score, smax, e0, e1);
    }
    for (int c = 0; c < nchunk; ++c) {
      long long e0 = (long long)c * chunkE;
      long long e1 = e0 + chunkE < E ? e0 + chunkE : E;
      int blocks = (int)((e1 - e0 + 63) / 64);
      if (nchunk > 1)
        gemm_e<0><<<blocks, 256, 0, stream>>>(edgef, wf1, hW1, h, src, dst,
                                              mbuf, score, smax, e0, e1);
      edge_accum<<<2048, 256, 0, stream>>>(mbuf, score, smax, dst,
                                           denom, wsum, e0, e1);
    }
    finalize_k<<<finB, 256, 0, stream>>>(y2, y3, wsum, denom, hout, N);
  }
}

// Round 4
// 1347.801 us; speedup vs baseline: 1.6174x; 1.6174x over previous
//
#include <hip/hip_runtime.h>

// Round 4: replace atomic scatter-softmax with dst-CSR gather.
// gemm_e epilogue writes m (f16) and score in dst-sorted (epos) order;
// gather_fin streams them per node: max, exp-accum, y2/y3 select, leaky.
// Fallback (ws too small for full m buffer): round-3 atomic path, chunked.

typedef unsigned short u16;
typedef short bf16x8 __attribute__((ext_vector_type(8)));
typedef float f32x4 __attribute__((ext_vector_type(4)));
typedef _Float16 f16x2 __attribute__((ext_vector_type(2)));

#define NEG_SLOPE 0.22916666666666666f

__device__ inline float bf2f(u16 h) { return __uint_as_float(((unsigned)h) << 16); }
__device__ inline u16 f2bf(float f) {
  unsigned u = __float_as_uint(f);
  u += 0x7fffu + ((u >> 16) & 1u);   // RNE
  return (u16)(u >> 16);
}
__device__ inline unsigned f2ord(float f) {
  unsigned u = __float_as_uint(f);
  return (u & 0x80000000u) ? ~u : (u | 0x80000000u);
}
__device__ inline float ord2f(unsigned u) {
  return __uint_as_float((u & 0x80000000u) ? (u & 0x7fffffffu) : ~u);
}

// ---------------------------------------------------------------------------
// Weight pre-split into MFMA-fragment-major bf16 hi/lo (B-frag for 16x16x32).
// ---------------------------------------------------------------------------
__global__ __launch_bounds__(256)
void prep_weights(const float* w0, const float* w1, const float* w2,
                  const float* w3, const float* w4, const float* w5,
                  const float* c0, const float* c1, const float* c2,
                  const float* c3, const float* c4, const float* c5,
                  u16* __restrict__ wf, float* __restrict__ bf) {
  int b = blockIdx.x, tid = threadIdx.x;
  const float* W = b == 0 ? w0 : b == 1 ? w1 : b == 2 ? w2 : b == 3 ? w3 : b == 4 ? w4 : w5;
  const float* C = b == 0 ? c0 : b == 1 ? c1 : b == 2 ? c2 : b == 3 ? c3 : b == 4 ? c4 : c5;
  u16* out = wf + (size_t)b * 32768;
  for (int q = 0; q < 64; ++q) {
    int fi = tid * 64 + q;
    int t = fi >> 11, kc = (fi >> 9) & 3, lane = (fi >> 3) & 63, j = fi & 7;
    int k = kc * 32 + (lane >> 4) * 8 + j;
    int n = t * 16 + (lane & 15);
    float w = W[k * 128 + n];
    u16 hi = f2bf(w);
    u16 lo = f2bf(w - bf2f(hi));
    int base = ((t * 4 + kc) * 2) * 512 + lane * 8 + j;
    out[base] = hi;
    out[base + 512] = lo;
  }
  if (tid < 128) bf[b * 128 + tid] = C[tid];
}

// ---------------------------------------------------------------------------
// CSR build: hist -> 3-step exclusive scan -> epos scatter.
// ---------------------------------------------------------------------------
__global__ __launch_bounds__(256)
void hist_k(const int* __restrict__ dst, int* __restrict__ deg, int E) {
  int i = blockIdx.x * 256 + threadIdx.x;
  int stride = gridDim.x * 256;
  for (; i < E; i += stride) atomicAdd(&deg[dst[i]], 1);
}

__global__ __launch_bounds__(256)
void scan1(const int* __restrict__ deg, int* __restrict__ off,
           int* __restrict__ bsum, int N) {
  __shared__ int sh[256];
  int b = blockIdx.x, t = threadIdx.x;
  int base = b * 1024 + t * 4;
  int v[4];
  #pragma unroll
  for (int i = 0; i < 4; ++i) v[i] = (base + i < N) ? deg[base + i] : 0;
  int s = v[0] + v[1] + v[2] + v[3];
  sh[t] = s;
  __syncthreads();
  for (int o = 1; o < 256; o <<= 1) {
    int x = (t >= o) ? sh[t - o] : 0;
    __syncthreads();
    sh[t] += x;
    __syncthreads();
  }
  int run = sh[t] - s;
  #pragma unroll
  for (int i = 0; i < 4; ++i) {
    if (base + i < N) off[base + i] = run;
    run += v[i];
  }
  if (t == 255) bsum[b] = sh[255];
}

__global__ void scan2(int* __restrict__ bsum, int nb) {
  __shared__ int sh[256];
  int t = threadIdx.x;
  int v = (t < nb) ? bsum[t] : 0;
  sh[t] = v;
  __syncthreads();
  for (int o = 1; o < 256; o <<= 1) {
    int x = (t >= o) ? sh[t - o] : 0;
    __syncthreads();
    sh[t] += x;
    __syncthreads();
  }
  if (t < nb) bsum[t] = sh[t] - v;
}

__global__ __launch_bounds__(256)
void scan3(int* __restrict__ off, const int* __restrict__ bsum,
           int* __restrict__ cursor, int N, int E) {
  int i = blockIdx.x * 256 + threadIdx.x;
  if (i < N) {
    int v = off[i] + bsum[i >> 10];
    off[i] = v;
    cursor[i] = v;
  } else if (i == N) {
    off[N] = E;
  }
}

__global__ __launch_bounds__(256)
void scatter_k(const int* __restrict__ dst, int* __restrict__ cursor,
               int* __restrict__ epos, int E) {
  int i = blockIdx.x * 256 + threadIdx.x;
  int stride = gridDim.x * 256;
  for (; i < E; i += stride) epos[i] = atomicAdd(&cursor[dst[i]], 1);
}

// ---------------------------------------------------------------------------
// C_f32[M,128] = A_f32[M,128] @ W (+bias), bf16x3 MFMA.
// ---------------------------------------------------------------------------
__global__ __launch_bounds__(256)
void gemm_n(const float* __restrict__ A, const u16* __restrict__ wf,
            const float* __restrict__ bias, float* __restrict__ C, int M) {
  __shared__ u16 ah[64 * 136];
  __shared__ u16 al[64 * 136];
  const int tid = threadIdx.x;
  const long long rowBase = (long long)blockIdx.x * 64;
  #pragma unroll
  for (int it = 0; it < 8; ++it) {
    int idx = it * 256 + tid;
    int row = idx >> 5, c4 = idx & 31;
    long long gr = rowBase + row;
    float4 v = make_float4(0.f, 0.f, 0.f, 0.f);
    if (gr < M) v = ((const float4*)A)[gr * 32 + c4];
    u16 hb[4] = {f2bf(v.x), f2bf(v.y), f2bf(v.z), f2bf(v.w)};
    u16 lb[4] = {f2bf(v.x - bf2f(hb[0])), f2bf(v.y - bf2f(hb[1])),
                 f2bf(v.z - bf2f(hb[2])), f2bf(v.w - bf2f(hb[3]))};
    *(uint2*)&ah[row * 136 + c4 * 4] = *(uint2*)hb;
    *(uint2*)&al[row * 136 + c4 * 4] = *(uint2*)lb;
  }
  __syncthreads();
  const int wid = tid >> 6, lane = tid & 63, lrow = lane & 15, lk = lane >> 4;
  bf16x8 af[4], alf[4];
  #pragma unroll
  for (int kc = 0; kc < 4; ++kc) {
    af[kc]  = *(const bf16x8*)&ah[(wid * 16 + lrow) * 136 + kc * 32 + lk * 8];
    alf[kc] = *(const bf16x8*)&al[(wid * 16 + lrow) * 136 + kc * 32 + lk * 8];
  }
  f32x4 acc[8];
  #pragma unroll
  for (int t = 0; t < 8; ++t) acc[t] = (f32x4){0.f, 0.f, 0.f, 0.f};
  #pragma unroll
  for (int t = 0; t < 8; ++t) {
    #pragma unroll
    for (int kc = 0; kc < 4; ++kc) {
      bf16x8 bh = *(const bf16x8*)&wf[((t * 4 + kc) * 2) * 512 + lane * 8];
      bf16x8 bl = *(const bf16x8*)&wf[((t * 4 + kc) * 2 + 1) * 512 + lane * 8];
      acc[t] = __builtin_amdgcn_mfma_f32_16x16x32_bf16(af[kc],  bh, acc[t], 0, 0, 0);
      acc[t] = __builtin_amdgcn_mfma_f32_16x16x32_bf16(alf[kc], bh, acc[t], 0, 0, 0);
      acc[t] = __builtin_amdgcn_mfma_f32_16x16x32_bf16(af[kc],  bl, acc[t], 0, 0, 0);
    }
  }
  #pragma unroll
  for (int t = 0; t < 8; ++t) {
    int col = t * 16 + lrow;
    float bv = bias[col];
    #pragma unroll
    for (int r = 0; r < 4; ++r) {
      long long row = rowBase + wid * 16 + lk * 4 + r;
      if (row < M) C[row * 128 + col] = acc[t][r] + bv;
    }
  }
}

// ---------------------------------------------------------------------------
// Edge GEMM + epilogue. MODE: 0 = m only, chunk-local edge order (fallback
// recompute); 1 = score + atomicMax smax + edge-order m (fallback pass 1);
// 2 = score + m written at epos[e] (CSR path, no atomics).
// ---------------------------------------------------------------------------
template<int MODE>
__global__ __launch_bounds__(256)
void gemm_e(const float* __restrict__ A, const u16* __restrict__ wf,
            const float* __restrict__ hW1, const float* __restrict__ hvec,
            const int* __restrict__ src, const int* __restrict__ dst,
            const int* __restrict__ epos, u16* __restrict__ mout,
            float* __restrict__ score, unsigned* __restrict__ smax,
            long long e0, long long e1) {
  __shared__ __align__(16) char smem[34816];
  u16* ah = (u16*)smem;
  u16* al = (u16*)(smem + 17408);
  float* msh = (float*)smem;             // aliases ah/al after barrier
  const int tid = threadIdx.x;
  const long long rowBase = e0 + (long long)blockIdx.x * 64;
  #pragma unroll
  for (int it = 0; it < 8; ++it) {
    int idx = it * 256 + tid;
    int row = idx >> 5, c4 = idx & 31;
    long long gr = rowBase + row;
    float4 v = make_float4(0.f, 0.f, 0.f, 0.f);
    if (gr < e1) v = ((const float4*)A)[gr * 32 + c4];
    u16 hb[4] = {f2bf(v.x), f2bf(v.y), f2bf(v.z), f2bf(v.w)};
    u16 lb[4] = {f2bf(v.x - bf2f(hb[0])), f2bf(v.y - bf2f(hb[1])),
                 f2bf(v.z - bf2f(hb[2])), f2bf(v.w - bf2f(hb[3]))};
    *(uint2*)&ah[row * 136 + c4 * 4] = *(uint2*)hb;
    *(uint2*)&al[row * 136 + c4 * 4] = *(uint2*)lb;
  }
  __syncthreads();
  const int wid = tid >> 6, lane = tid & 63, lrow = lane & 15, lk = lane >> 4;
  bf16x8 af[4], alf[4];
  #pragma unroll
  for (int kc = 0; kc < 4; ++kc) {
    af[kc]  = *(const bf16x8*)&ah[(wid * 16 + lrow) * 136 + kc * 32 + lk * 8];
    alf[kc] = *(const bf16x8*)&al[(wid * 16 + lrow) * 136 + kc * 32 + lk * 8];
  }
  f32x4 acc[8];
  #pragma unroll
  for (int t = 0; t < 8; ++t) acc[t] = (f32x4){0.f, 0.f, 0.f, 0.f};
  #pragma unroll
  for (int t = 0; t < 8; ++t) {
    #pragma unroll
    for (int kc = 0; kc < 4; ++kc) {
      bf16x8 bh = *(const bf16x8*)&wf[((t * 4 + kc) * 2) * 512 + lane * 8];
      bf16x8 bl = *(const bf16x8*)&wf[((t * 4 + kc) * 2 + 1) * 512 + lane * 8];
      acc[t] = __builtin_amdgcn_mfma_f32_16x16x32_bf16(af[kc],  bh, acc[t], 0, 0, 0);
      acc[t] = __builtin_amdgcn_mfma_f32_16x16x32_bf16(alf[kc], bh, acc[t], 0, 0, 0);
      acc[t] = __builtin_amdgcn_mfma_f32_16x16x32_bf16(af[kc],  bl, acc[t], 0, 0, 0);
    }
  }
  __syncthreads();
  #pragma unroll
  for (int t = 0; t < 8; ++t)
    #pragma unroll
    for (int r = 0; r < 4; ++r)
      msh[(wid * 16 + lk * 4 + r) * 132 + t * 16 + lrow] = acc[t][r];
  __syncthreads();

  const int r = tid >> 2, p = tid & 3;
  const long long e = rowBase + r;
  float sc = 0.f;
  int d = 0;
  if (e < e1) {
    int s = src[e];
    d = dst[e];
    const float* hw = hW1 + (size_t)s * 128 + p * 32;
    const float* hd = hvec + (size_t)d * 128 + p * 32;
    _Float16 mb[32];
    #pragma unroll
    for (int i = 0; i < 32; i += 4) {
      float4 a = *(const float4*)&msh[r * 132 + p * 32 + i];
      float4 b = *(const float4*)&hw[i];
      float m0 = a.x + b.x, m1 = a.y + b.y, m2 = a.z + b.z, m3 = a.w + b.w;
      mb[i] = (_Float16)m0; mb[i + 1] = (_Float16)m1;
      mb[i + 2] = (_Float16)m2; mb[i + 3] = (_Float16)m3;
      if (MODE >= 1) {
        float4 hh = *(const float4*)&hd[i];
        sc += m0 * hh.x + m1 * hh.y + m2 * hh.z + m3 * hh.w;
      }
    }
    size_t mrowIdx = (MODE == 2) ? (size_t)epos[e] : (size_t)(e - e0);
    u16* mrow = mout + mrowIdx * 128 + p * 32;
    #pragma unroll
    for (int i = 0; i < 4; ++i)
      *(uint4*)&mrow[i * 8] = ((uint4*)mb)[i];
  }
  if (MODE >= 1) {
    sc += __shfl_xor(sc, 1);
    sc += __shfl_xor(sc, 2);
    if (p == 0 && e < e1) {
      if (MODE == 2) {
        score[epos[e]] = sc;
      } else {
        score[e] = sc;
        atomicMax(&smax[d], f2ord(sc));
      }
    }
  }
}

// ---------------------------------------------------------------------------
// CSR gather + finalize: one wave per node. max -> exp-accum -> y2/y3 -> leaky.
// m and score are in dst-sorted position order (fully streaming reads).
// ---------------------------------------------------------------------------
__global__ __launch_bounds__(256)
void gather_fin(const u16* __restrict__ m, const float* __restrict__ score,
                const int* __restrict__ off, const float* __restrict__ y2,
                const float* __restrict__ y3, float* __restrict__ out, int N) {
  int node = blockIdx.x * 4 + (threadIdx.x >> 6);
  if (node >= N) return;
  int lane = threadIdx.x & 63;
  int s0 = off[node], s1 = off[node + 1];
  size_t obase = (size_t)node * 128 + 2 * lane;
  float a, b;
  if (s1 == s0) {
    a = y3[obase];
    b = y3[obase + 1];
  } else {
    float mx = -3.4e38f;
    for (int i = s0 + lane; i < s1; i += 64) mx = fmaxf(mx, score[i]);
    #pragma unroll
    for (int o = 32; o > 0; o >>= 1) mx = fmaxf(mx, __shfl_xor(mx, o));
    float den = 0.f, accx = 0.f, accy = 0.f;
    for (int i = s0; i < s1; ++i) {
      float w = __expf(score[i] - mx);
      den += w;
      f16x2 mv = *(const f16x2*)&m[(size_t)i * 128 + 2 * lane];
      accx += w * (float)mv[0];
      accy += w * (float)mv[1];
    }
    float inv = 1.f / den;       // den >= 1 (max term)
    a = y2[obase]     + accx * inv;
    b = y2[obase + 1] + accy * inv;
  }
  a = a >= 0.f ? a : a * NEG_SLOPE;
  b = b >= 0.f ? b : b * NEG_SLOPE;
  *(float2*)&out[obase] = make_float2(a, b);
}

// ---------------------------------------------------------------------------
// Fallback kernels (round-3 atomic path).
// ---------------------------------------------------------------------------
__global__ __launch_bounds__(256)
void edge_accum(const u16* __restrict__ m, const float* __restrict__ score,
                const unsigned* __restrict__ smax, const int* __restrict__ dst,
                float* __restrict__ denom, float* __restrict__ wsum,
                long long e0, long long e1) {
  const int lane = threadIdx.x & 63;
  const long long w0 = ((long long)blockIdx.x * blockDim.x + threadIdx.x) >> 6;
  const long long nw = ((long long)gridDim.x * blockDim.x) >> 6;
  for (long long e = e0 + w0; e < e1; e += nw) {
    int d = dst[e];
    float w = __expf(score[e] - ord2f(smax[d]));
    f16x2 mv = *(const f16x2*)&m[(size_t)(e - e0) * 128 + 2 * lane];
    size_t base = (size_t)d * 128 + 2 * lane;
    atomicAdd(&wsum[base],     w * (float)mv[0]);
    atomicAdd(&wsum[base + 1], w * (float)mv[1]);
    if (lane == 0) atomicAdd(&denom[d], w);
  }
}

__global__ __launch_bounds__(256)
void finalize_k(const float* __restrict__ y2, const float* __restrict__ y3,
                const float* __restrict__ wsum, const float* __restrict__ denom,
                float* __restrict__ out, int N) {
  long long gid = (long long)blockIdx.x * 256 + threadIdx.x;
  if (gid >= (long long)N * 64) return;
  int n = (int)(gid >> 6);
  size_t base = (size_t)gid * 2;
  float den = denom[n];
  float a, b;
  if (den > 0.f) {
    float inv = 1.f / den;
    a = y2[base]     + wsum[base]     * inv;
    b = y2[base + 1] + wsum[base + 1] * inv;
  } else {
    a = y3[base];
    b = y3[base + 1];
  }
  a = a >= 0.f ? a : a * NEG_SLOPE;
  b = b >= 0.f ? b : b * NEG_SLOPE;
  *(float2*)&out[base] = make_float2(a, b);
}

extern "C" void kernel_launch(void* const* d_in, const int* in_sizes, int n_in,
                              void* d_out, int out_size, void* d_ws, size_t ws_size,
                              hipStream_t stream) {
  const int D = 128;
  const int N = in_sizes[0] / D;
  const int E = in_sizes[1] / D;

  const float* node  = (const float*)d_in[0];
  const float* edgef = (const float*)d_in[1];
  const int* src = (const int*)d_in[2];
  const int* dst = (const int*)d_in[3];

  // workspace carve (256B-aligned chunks)
  char* p = (char*)d_ws;
  u16*   wfrag = (u16*)p;    p += (size_t)6 * 32768 * 2;
  float* biasf = (float*)p;  p += 4096;
  float* hW1   = (float*)p;  p += (size_t)N * 512;
  float* y2    = (float*)p;  p += (size_t)N * 512;
  float* y3    = (float*)p;  p += (size_t)N * 512;
  float* h1    = (float*)p;  p += (size_t)N * 512;
  float* score = (float*)p;  p += (size_t)E * 4;
  unsigned* smax = (unsigned*)p; p += (size_t)N * 4;   // fallback zero region
  float* denom = (float*)p;      p += (size_t)N * 4;
  float* wsum  = (float*)p;      p += (size_t)N * 512;
  size_t zbytes = (size_t)N * (2 + D) * 4;
  int* deg    = (int*)p;     p += (size_t)N * 4;       // also cursor after scan3
  int* off    = (int*)p;     p += (size_t)(N + 256) * 4;
  int* cursor = (int*)p;     p += (size_t)N * 4;
  int* bsum   = (int*)p;     p += 1024;
  int* epos   = (int*)p;     p += (size_t)E * 4;
  u16* mbuf   = (u16*)p;
  size_t fixed = (size_t)(p - (char*)d_ws);

  const bool csr = (ws_size >= fixed + (size_t)E * 256);
  long long chunkE = E;
  if (!csr) {
    long long cap = (ws_size > fixed) ? ((long long)((ws_size - fixed) / 256) & ~63LL) : 64;
    if (cap < 64) cap = 64;
    if (cap < chunkE) chunkE = cap;
  }
  const int nchunk = (int)((E + chunkE - 1) / chunkE);

  prep_weights<<<6, 256, 0, stream>>>(
      (const float*)d_in[4],  (const float*)d_in[6],  (const float*)d_in[8],
      (const float*)d_in[10], (const float*)d_in[12], (const float*)d_in[14],
      (const float*)d_in[5],  (const float*)d_in[7],  (const float*)d_in[9],
      (const float*)d_in[11], (const float*)d_in[13], (const float*)d_in[15],
      wfrag, biasf);

  const int gN = (N + 63) / 64;
  const int finB = (N * 64 + 255) / 256;
  const int eB = (E + 255) / 256;
  const int nb = (N + 1023) / 1024;

  if (csr) {
    hipMemsetAsync(deg, 0, (size_t)N * 4, stream);
    hist_k<<<eB, 256, 0, stream>>>(dst, deg, E);
    scan1<<<nb, 256, 0, stream>>>(deg, off, bsum, N);
    scan2<<<1, 256, 0, stream>>>(bsum, nb);
    scan3<<<(N + 256) / 256, 256, 0, stream>>>(off, bsum, cursor, N, E);
    scatter_k<<<eB, 256, 0, stream>>>(dst, cursor, epos, E);
  }

  for (int l = 0; l < 2; ++l) {
    const float* h = (l == 0) ? node : h1;
    float* hout = (l == 0) ? h1 : (float*)d_out;
    const u16* wf1 = wfrag + (size_t)(l * 3 + 0) * 32768;
    const u16* wf2 = wfrag + (size_t)(l * 3 + 1) * 32768;
    const u16* wf3 = wfrag + (size_t)(l * 3 + 2) * 32768;
    const float* b1 = biasf + (l * 3 + 0) * 128;
    const float* b2 = biasf + (l * 3 + 1) * 128;
    const float* b3 = biasf + (l * 3 + 2) * 128;

    gemm_n<<<gN, 256, 0, stream>>>(h, wf1, b1, hW1, N);
    gemm_n<<<gN, 256, 0, stream>>>(h, wf2, b2, y2, N);
    gemm_n<<<gN, 256, 0, stream>>>(h, wf3, b3, y3, N);

    if (csr) {
      int blocks = (E + 63) / 64;
      gemm_e<2><<<blocks, 256, 0, stream>>>(edgef, wf1, hW1, h, src, dst,
                                            epos, mbuf, score, nullptr, 0, E);
      gather_fin<<<(N + 3) / 4, 256, 0, stream>>>(mbuf, score, off, y2, y3, hout, N);
    } else {
      hipMemsetAsync(smax, 0, zbytes, stream);
      for (int c = 0; c < nchunk; ++c) {
        long long e0 = (long long)c * chunkE;
        long long e1 = e0 + chunkE < E ? e0 + chunkE : E;
        int blocks = (int)((e1 - e0 + 63) / 64);
        gemm_e<1><<<blocks, 256, 0, stream>>>(edgef, wf1, hW1, h, src, dst,
                                              nullptr, mbuf, score, smax, e0, e1);
      }
      for (int c = 0; c < nchunk; ++c) {
        long long e0 = (long long)c * chunkE;
        long long e1 = e0 + chunkE < E ? e0 + chunkE : E;
        int blocks = (int)((e1 - e0 + 63) / 64);
        if (nchunk > 1)
          gemm_e<0><<<blocks, 256, 0, stream>>>(edgef, wf1, hW1, h, src, dst,
                                                nullptr, mbuf, score, nullptr, e0, e1);
        edge_accum<<<2048, 256, 0, stream>>>(mbuf, score, smax, dst,
                                             denom, wsum, e0, e1);
      }
      finalize_k<<<finB, 256, 0, stream>>>(y2, y3, wsum, denom, hout, N);
    }
  }
}

// Round 5
// 1322.457 us; speedup vs baseline: 1.6484x; 1.0192x over previous
//
#include <hip/hip_runtime.h>

// Round 5: gemm_e gather prefetch (hW1[src], h[dst] rows loaded into regs before
// the MFMA section so ~600cyc random-gather latency overlaps compute), and the
// three node GEMMs fused into gemm_n3 (stage h once, 3 weight sets).
// Pipeline otherwise round-4: CSR build, gemm_e epilogue writes m/score in
// dst-sorted order, gather_fin streams them. Fallback atomic path kept.

typedef unsigned short u16;
typedef short bf16x8 __attribute__((ext_vector_type(8)));
typedef float f32x4 __attribute__((ext_vector_type(4)));
typedef _Float16 f16x2 __attribute__((ext_vector_type(2)));

#define NEG_SLOPE 0.22916666666666666f

__device__ inline float bf2f(u16 h) { return __uint_as_float(((unsigned)h) << 16); }
__device__ inline u16 f2bf(float f) {
  unsigned u = __float_as_uint(f);
  u += 0x7fffu + ((u >> 16) & 1u);   // RNE
  return (u16)(u >> 16);
}
__device__ inline unsigned f2ord(float f) {
  unsigned u = __float_as_uint(f);
  return (u & 0x80000000u) ? ~u : (u | 0x80000000u);
}
__device__ inline float ord2f(unsigned u) {
  return __uint_as_float((u & 0x80000000u) ? (u & 0x7fffffffu) : ~u);
}

// ---------------------------------------------------------------------------
// Weight pre-split into MFMA-fragment-major bf16 hi/lo (B-frag for 16x16x32).
// ---------------------------------------------------------------------------
__global__ __launch_bounds__(256)
void prep_weights(const float* w0, const float* w1, const float* w2,
                  const float* w3, const float* w4, const float* w5,
                  const float* c0, const float* c1, const float* c2,
                  const float* c3, const float* c4, const float* c5,
                  u16* __restrict__ wf, float* __restrict__ bf) {
  int b = blockIdx.x, tid = threadIdx.x;
  const float* W = b == 0 ? w0 : b == 1 ? w1 : b == 2 ? w2 : b == 3 ? w3 : b == 4 ? w4 : w5;
  const float* C = b == 0 ? c0 : b == 1 ? c1 : b == 2 ? c2 : b == 3 ? c3 : b == 4 ? c4 : c5;
  u16* out = wf + (size_t)b * 32768;
  for (int q = 0; q < 64; ++q) {
    int fi = tid * 64 + q;
    int t = fi >> 11, kc = (fi >> 9) & 3, lane = (fi >> 3) & 63, j = fi & 7;
    int k = kc * 32 + (lane >> 4) * 8 + j;
    int n = t * 16 + (lane & 15);
    float w = W[k * 128 + n];
    u16 hi = f2bf(w);
    u16 lo = f2bf(w - bf2f(hi));
    int base = ((t * 4 + kc) * 2) * 512 + lane * 8 + j;
    out[base] = hi;
    out[base + 512] = lo;
  }
  if (tid < 128) bf[b * 128 + tid] = C[tid];
}

// ---------------------------------------------------------------------------
// CSR build: hist -> 3-step exclusive scan -> epos scatter.
// ---------------------------------------------------------------------------
__global__ __launch_bounds__(256)
void hist_k(const int* __restrict__ dst, int* __restrict__ deg, int E) {
  int i = blockIdx.x * 256 + threadIdx.x;
  int stride = gridDim.x * 256;
  for (; i < E; i += stride) atomicAdd(&deg[dst[i]], 1);
}

__global__ __launch_bounds__(256)
void scan1(const int* __restrict__ deg, int* __restrict__ off,
           int* __restrict__ bsum, int N) {
  __shared__ int sh[256];
  int b = blockIdx.x, t = threadIdx.x;
  int base = b * 1024 + t * 4;
  int v[4];
  #pragma unroll
  for (int i = 0; i < 4; ++i) v[i] = (base + i < N) ? deg[base + i] : 0;
  int s = v[0] + v[1] + v[2] + v[3];
  sh[t] = s;
  __syncthreads();
  for (int o = 1; o < 256; o <<= 1) {
    int x = (t >= o) ? sh[t - o] : 0;
    __syncthreads();
    sh[t] += x;
    __syncthreads();
  }
  int run = sh[t] - s;
  #pragma unroll
  for (int i = 0; i < 4; ++i) {
    if (base + i < N) off[base + i] = run;
    run += v[i];
  }
  if (t == 255) bsum[b] = sh[255];
}

__global__ void scan2(int* __restrict__ bsum, int nb) {
  __shared__ int sh[256];
  int t = threadIdx.x;
  int v = (t < nb) ? bsum[t] : 0;
  sh[t] = v;
  __syncthreads();
  for (int o = 1; o < 256; o <<= 1) {
    int x = (t >= o) ? sh[t - o] : 0;
    __syncthreads();
    sh[t] += x;
    __syncthreads();
  }
  if (t < nb) bsum[t] = sh[t] - v;
}

__global__ __launch_bounds__(256)
void scan3(int* __restrict__ off, const int* __restrict__ bsum,
           int* __restrict__ cursor, int N, int E) {
  int i = blockIdx.x * 256 + threadIdx.x;
  if (i < N) {
    int v = off[i] + bsum[i >> 10];
    off[i] = v;
    cursor[i] = v;
  } else if (i == N) {
    off[N] = E;
  }
}

__global__ __launch_bounds__(256)
void scatter_k(const int* __restrict__ dst, int* __restrict__ cursor,
               int* __restrict__ epos, int E) {
  int i = blockIdx.x * 256 + threadIdx.x;
  int stride = gridDim.x * 256;
  for (; i < E; i += stride) epos[i] = atomicAdd(&cursor[dst[i]], 1);
}

// ---------------------------------------------------------------------------
// Fused node GEMMs: stage A once, apply 3 weight sets -> hW1, y2, y3.
// ---------------------------------------------------------------------------
__global__ __launch_bounds__(256)
void gemm_n3(const float* __restrict__ A,
             const u16* __restrict__ wfa, const u16* __restrict__ wfb,
             const u16* __restrict__ wfc, const float* __restrict__ biases,
             float* __restrict__ C0, float* __restrict__ C1,
             float* __restrict__ C2, int M) {
  __shared__ u16 ah[64 * 136];
  __shared__ u16 al[64 * 136];
  const int tid = threadIdx.x;
  const long long rowBase = (long long)blockIdx.x * 64;
  #pragma unroll
  for (int it = 0; it < 8; ++it) {
    int idx = it * 256 + tid;
    int row = idx >> 5, c4 = idx & 31;
    long long gr = rowBase + row;
    float4 v = make_float4(0.f, 0.f, 0.f, 0.f);
    if (gr < M) v = ((const float4*)A)[gr * 32 + c4];
    u16 hb[4] = {f2bf(v.x), f2bf(v.y), f2bf(v.z), f2bf(v.w)};
    u16 lb[4] = {f2bf(v.x - bf2f(hb[0])), f2bf(v.y - bf2f(hb[1])),
                 f2bf(v.z - bf2f(hb[2])), f2bf(v.w - bf2f(hb[3]))};
    *(uint2*)&ah[row * 136 + c4 * 4] = *(uint2*)hb;
    *(uint2*)&al[row * 136 + c4 * 4] = *(uint2*)lb;
  }
  __syncthreads();
  const int wid = tid >> 6, lane = tid & 63, lrow = lane & 15, lk = lane >> 4;
  bf16x8 af[4], alf[4];
  #pragma unroll
  for (int kc = 0; kc < 4; ++kc) {
    af[kc]  = *(const bf16x8*)&ah[(wid * 16 + lrow) * 136 + kc * 32 + lk * 8];
    alf[kc] = *(const bf16x8*)&al[(wid * 16 + lrow) * 136 + kc * 32 + lk * 8];
  }
  const u16* wfs[3] = {wfa, wfb, wfc};
  float* Cs[3] = {C0, C1, C2};
  for (int m = 0; m < 3; ++m) {
    const u16* wf = wfs[m];
    float* C = Cs[m];
    const float* bias = biases + m * 128;
    f32x4 acc[8];
    #pragma unroll
    for (int t = 0; t < 8; ++t) acc[t] = (f32x4){0.f, 0.f, 0.f, 0.f};
    #pragma unroll
    for (int t = 0; t < 8; ++t) {
      #pragma unroll
      for (int kc = 0; kc < 4; ++kc) {
        bf16x8 bh = *(const bf16x8*)&wf[((t * 4 + kc) * 2) * 512 + lane * 8];
        bf16x8 bl = *(const bf16x8*)&wf[((t * 4 + kc) * 2 + 1) * 512 + lane * 8];
        acc[t] = __builtin_amdgcn_mfma_f32_16x16x32_bf16(af[kc],  bh, acc[t], 0, 0, 0);
        acc[t] = __builtin_amdgcn_mfma_f32_16x16x32_bf16(alf[kc], bh, acc[t], 0, 0, 0);
        acc[t] = __builtin_amdgcn_mfma_f32_16x16x32_bf16(af[kc],  bl, acc[t], 0, 0, 0);
      }
    }
    #pragma unroll
    for (int t = 0; t < 8; ++t) {
      int col = t * 16 + lrow;
      float bv = bias[col];
      #pragma unroll
      for (int r = 0; r < 4; ++r) {
        long long row = rowBase + wid * 16 + lk * 4 + r;
        if (row < M) C[row * 128 + col] = acc[t][r] + bv;
      }
    }
  }
}

// ---------------------------------------------------------------------------
// Edge GEMM + fused epilogue. Gathers (src/dst/epos + hW1/h rows) issued
// BEFORE the MFMA section so their latency overlaps compute.
// MODE: 0 = m only (fallback recompute); 1 = +score/atomicMax (fallback);
// 2 = score + m at epos[e] (CSR path).
// ---------------------------------------------------------------------------
template<int MODE>
__global__ __launch_bounds__(256)
void gemm_e(const float* __restrict__ A, const u16* __restrict__ wf,
            const float* __restrict__ hW1, const float* __restrict__ hvec,
            const int* __restrict__ src, const int* __restrict__ dst,
            const int* __restrict__ epos, u16* __restrict__ mout,
            float* __restrict__ score, unsigned* __restrict__ smax,
            long long e0, long long e1) {
  __shared__ __align__(16) char smem[34816];
  u16* ah = (u16*)smem;
  u16* al = (u16*)(smem + 17408);
  float* msh = (float*)smem;             // aliases ah/al after barrier
  const int tid = threadIdx.x;
  const long long rowBase = e0 + (long long)blockIdx.x * 64;

  // ---- staging loads (A tile) ----
  #pragma unroll
  for (int it = 0; it < 8; ++it) {
    int idx = it * 256 + tid;
    int row = idx >> 5, c4 = idx & 31;
    long long gr = rowBase + row;
    float4 v = make_float4(0.f, 0.f, 0.f, 0.f);
    if (gr < e1) v = ((const float4*)A)[gr * 32 + c4];
    u16 hb[4] = {f2bf(v.x), f2bf(v.y), f2bf(v.z), f2bf(v.w)};
    u16 lb[4] = {f2bf(v.x - bf2f(hb[0])), f2bf(v.y - bf2f(hb[1])),
                 f2bf(v.z - bf2f(hb[2])), f2bf(v.w - bf2f(hb[3]))};
    *(uint2*)&ah[row * 136 + c4 * 4] = *(uint2*)hb;
    *(uint2*)&al[row * 136 + c4 * 4] = *(uint2*)lb;
  }

  // ---- gather prefetch (independent of LDS; overlaps staging + MFMA) ----
  const int r = tid >> 2, p = tid & 3;
  const long long e = rowBase + r;
  const bool ev = (e < e1);
  int s = 0, d = 0, ep = 0;
  if (ev) {
    s = src[e];
    d = dst[e];
    if (MODE == 2) ep = epos[e];
  }
  float4 hwr[8], hdr[8];
  if (ev) {
    const float4* hwp = (const float4*)(hW1 + (size_t)s * 128 + p * 32);
    #pragma unroll
    for (int i = 0; i < 8; ++i) hwr[i] = hwp[i];
    if (MODE >= 1) {
      const float4* hdp = (const float4*)(hvec + (size_t)d * 128 + p * 32);
      #pragma unroll
      for (int i = 0; i < 8; ++i) hdr[i] = hdp[i];
    }
  }

  __syncthreads();
  const int wid = tid >> 6, lane = tid & 63, lrow = lane & 15, lk = lane >> 4;
  bf16x8 af[4], alf[4];
  #pragma unroll
  for (int kc = 0; kc < 4; ++kc) {
    af[kc]  = *(const bf16x8*)&ah[(wid * 16 + lrow) * 136 + kc * 32 + lk * 8];
    alf[kc] = *(const bf16x8*)&al[(wid * 16 + lrow) * 136 + kc * 32 + lk * 8];
  }
  f32x4 acc[8];
  #pragma unroll
  for (int t = 0; t < 8; ++t) acc[t] = (f32x4){0.f, 0.f, 0.f, 0.f};
  #pragma unroll
  for (int t = 0; t < 8; ++t) {
    #pragma unroll
    for (int kc = 0; kc < 4; ++kc) {
      bf16x8 bh = *(const bf16x8*)&wf[((t * 4 + kc) * 2) * 512 + lane * 8];
      bf16x8 bl = *(const bf16x8*)&wf[((t * 4 + kc) * 2 + 1) * 512 + lane * 8];
      acc[t] = __builtin_amdgcn_mfma_f32_16x16x32_bf16(af[kc],  bh, acc[t], 0, 0, 0);
      acc[t] = __builtin_amdgcn_mfma_f32_16x16x32_bf16(alf[kc], bh, acc[t], 0, 0, 0);
      acc[t] = __builtin_amdgcn_mfma_f32_16x16x32_bf16(af[kc],  bl, acc[t], 0, 0, 0);
    }
  }
  __syncthreads();   // all waves done reading ah/al before msh overwrite
  #pragma unroll
  for (int t = 0; t < 8; ++t)
    #pragma unroll
    for (int q = 0; q < 4; ++q)
      msh[(wid * 16 + lk * 4 + q) * 132 + t * 16 + lrow] = acc[t][q];
  __syncthreads();

  float sc = 0.f;
  if (ev) {
    _Float16 mb[32];
    #pragma unroll
    for (int i = 0; i < 8; ++i) {
      float4 a = *(const float4*)&msh[r * 132 + p * 32 + i * 4];
      float4 b = hwr[i];
      float m0 = a.x + b.x, m1 = a.y + b.y, m2 = a.z + b.z, m3 = a.w + b.w;
      mb[i * 4] = (_Float16)m0; mb[i * 4 + 1] = (_Float16)m1;
      mb[i * 4 + 2] = (_Float16)m2; mb[i * 4 + 3] = (_Float16)m3;
      if (MODE >= 1) {
        float4 hh = hdr[i];
        sc += m0 * hh.x + m1 * hh.y + m2 * hh.z + m3 * hh.w;
      }
    }
    size_t mrowIdx = (MODE == 2) ? (size_t)ep : (size_t)(e - e0);
    u16* mrow = mout + mrowIdx * 128 + p * 32;
    #pragma unroll
    for (int i = 0; i < 4; ++i)
      *(uint4*)&mrow[i * 8] = ((uint4*)mb)[i];
  }
  if (MODE >= 1) {
    sc += __shfl_xor(sc, 1);
    sc += __shfl_xor(sc, 2);
    if (p == 0 && ev) {
      if (MODE == 2) {
        score[ep] = sc;
      } else {
        score[e] = sc;
        atomicMax(&smax[d], f2ord(sc));
      }
    }
  }
}

// ---------------------------------------------------------------------------
// CSR gather + finalize: one wave per node (streaming m/score).
// ---------------------------------------------------------------------------
__global__ __launch_bounds__(256)
void gather_fin(const u16* __restrict__ m, const float* __restrict__ score,
                const int* __restrict__ off, const float* __restrict__ y2,
                const float* __restrict__ y3, float* __restrict__ out, int N) {
  int node = blockIdx.x * 4 + (threadIdx.x >> 6);
  if (node >= N) return;
  int lane = threadIdx.x & 63;
  int s0 = off[node], s1 = off[node + 1];
  size_t obase = (size_t)node * 128 + 2 * lane;
  float a, b;
  if (s1 == s0) {
    a = y3[obase];
    b = y3[obase + 1];
  } else {
    float mx = -3.4e38f;
    for (int i = s0 + lane; i < s1; i += 64) mx = fmaxf(mx, score[i]);
    #pragma unroll
    for (int o = 32; o > 0; o >>= 1) mx = fmaxf(mx, __shfl_xor(mx, o));
    float den = 0.f, accx = 0.f, accy = 0.f;
    for (int i = s0; i < s1; ++i) {
      float w = __expf(score[i] - mx);
      den += w;
      f16x2 mv = *(const f16x2*)&m[(size_t)i * 128 + 2 * lane];
      accx += w * (float)mv[0];
      accy += w * (float)mv[1];
    }
    float inv = 1.f / den;       // den >= 1 (max term present)
    a = y2[obase]     + accx * inv;
    b = y2[obase + 1] + accy * inv;
  }
  a = a >= 0.f ? a : a * NEG_SLOPE;
  b = b >= 0.f ? b : b * NEG_SLOPE;
  *(float2*)&out[obase] = make_float2(a, b);
}

// ---------------------------------------------------------------------------
// Fallback kernels (atomic path, ws too small).
// ---------------------------------------------------------------------------
__global__ __launch_bounds__(256)
void edge_accum(const u16* __restrict__ m, const float* __restrict__ score,
                const unsigned* __restrict__ smax, const int* __restrict__ dst,
                float* __restrict__ denom, float* __restrict__ wsum,
                long long e0, long long e1) {
  const int lane = threadIdx.x & 63;
  const long long w0 = ((long long)blockIdx.x * blockDim.x + threadIdx.x) >> 6;
  const long long nw = ((long long)gridDim.x * blockDim.x) >> 6;
  for (long long e = e0 + w0; e < e1; e += nw) {
    int d = dst[e];
    float w = __expf(score[e] - ord2f(smax[d]));
    f16x2 mv = *(const f16x2*)&m[(size_t)(e - e0) * 128 + 2 * lane];
    size_t base = (size_t)d * 128 + 2 * lane;
    atomicAdd(&wsum[base],     w * (float)mv[0]);
    atomicAdd(&wsum[base + 1], w * (float)mv[1]);
    if (lane == 0) atomicAdd(&denom[d], w);
  }
}

__global__ __launch_bounds__(256)
void finalize_k(const float* __restrict__ y2, const float* __restrict__ y3,
                const float* __restrict__ wsum, const float* __restrict__ denom,
                float* __restrict__ out, int N) {
  long long gid = (long long)blockIdx.x * 256 + threadIdx.x;
  if (gid >= (long long)N * 64) return;
  int n = (int)(gid >> 6);
  size_t base = (size_t)gid * 2;
  float den = denom[n];
  float a, b;
  if (den > 0.f) {
    float inv = 1.f / den;
    a = y2[base]     + wsum[base]     * inv;
    b = y2[base + 1] + wsum[base + 1] * inv;
  } else {
    a = y3[base];
    b = y3[base + 1];
  }
  a = a >= 0.f ? a : a * NEG_SLOPE;
  b = b >= 0.f ? b : b * NEG_SLOPE;
  *(float2*)&out[base] = make_float2(a, b);
}

extern "C" void kernel_launch(void* const* d_in, const int* in_sizes, int n_in,
                              void* d_out, int out_size, void* d_ws, size_t ws_size,
                              hipStream_t stream) {
  const int D = 128;
  const int N = in_sizes[0] / D;
  const int E = in_sizes[1] / D;

  const float* node  = (const float*)d_in[0];
  const float* edgef = (const float*)d_in[1];
  const int* src = (const int*)d_in[2];
  const int* dst = (const int*)d_in[3];

  // workspace carve (256B-aligned chunks)
  char* p = (char*)d_ws;
  u16*   wfrag = (u16*)p;    p += (size_t)6 * 32768 * 2;
  float* biasf = (float*)p;  p += 4096;
  float* hW1   = (float*)p;  p += (size_t)N * 512;
  float* y2    = (float*)p;  p += (size_t)N * 512;
  float* y3    = (float*)p;  p += (size_t)N * 512;
  float* h1    = (float*)p;  p += (size_t)N * 512;
  float* score = (float*)p;  p += (size_t)E * 4;
  unsigned* smax = (unsigned*)p; p += (size_t)N * 4;   // fallback zero region
  float* denom = (float*)p;      p += (size_t)N * 4;
  float* wsum  = (float*)p;      p += (size_t)N * 512;
  size_t zbytes = (size_t)N * (2 + D) * 4;
  int* deg    = (int*)p;     p += (size_t)N * 4;
  int* off    = (int*)p;     p += (size_t)(N + 256) * 4;
  int* cursor = (int*)p;     p += (size_t)N * 4;
  int* bsum   = (int*)p;     p += 1024;
  int* epos   = (int*)p;     p += (size_t)E * 4;
  u16* mbuf   = (u16*)p;
  size_t fixed = (size_t)(p - (char*)d_ws);

  const bool csr = (ws_size >= fixed + (size_t)E * 256);
  long long chunkE = E;
  if (!csr) {
    long long cap = (ws_size > fixed) ? ((long long)((ws_size - fixed) / 256) & ~63LL) : 64;
    if (cap < 64) cap = 64;
    if (cap < chunkE) chunkE = cap;
  }
  const int nchunk = (int)((E + chunkE - 1) / chunkE);

  prep_weights<<<6, 256, 0, stream>>>(
      (const float*)d_in[4],  (const float*)d_in[6],  (const float*)d_in[8],
      (const float*)d_in[10], (const float*)d_in[12], (const float*)d_in[14],
      (const float*)d_in[5],  (const float*)d_in[7],  (const float*)d_in[9],
      (const float*)d_in[11], (const float*)d_in[13], (const float*)d_in[15],
      wfrag, biasf);

  const int gN = (N + 63) / 64;
  const int finB = (N * 64 + 255) / 256;
  const int eB = (E + 255) / 256;
  const int nb = (N + 1023) / 1024;

  if (csr) {
    hipMemsetAsync(deg, 0, (size_t)N * 4, stream);
    hist_k<<<eB, 256, 0, stream>>>(dst, deg, E);
    scan1<<<nb, 256, 0, stream>>>(deg, off, bsum, N);
    scan2<<<1, 256, 0, stream>>>(bsum, nb);
    scan3<<<(N + 256) / 256, 256, 0, stream>>>(off, bsum, cursor, N, E);
    scatter_k<<<eB, 256, 0, stream>>>(dst, cursor, epos, E);
  }

  for (int l = 0; l < 2; ++l) {
    const float* h = (l == 0) ? node : h1;
    float* hout = (l == 0) ? h1 : (float*)d_out;
    const u16* wf1 = wfrag + (size_t)(l * 3 + 0) * 32768;
    const u16* wf2 = wfrag + (size_t)(l * 3 + 1) * 32768;
    const u16* wf3 = wfrag + (size_t)(l * 3 + 2) * 32768;
    const float* bset = biasf + l * 384;   // [b1|b2|b3] for this layer

    gemm_n3<<<gN, 256, 0, stream>>>(h, wf1, wf2, wf3, bset, hW1, y2, y3, N);

    if (csr) {
      int blocks = (E + 63) / 64;
      gemm_e<2><<<blocks, 256, 0, stream>>>(edgef, wf1, hW1, h, src, dst,
                                            epos, mbuf, score, nullptr, 0, E);
      gather_fin<<<(N + 3) / 4, 256, 0, stream>>>(mbuf, score, off, y2, y3, hout, N);
    } else {
      hipMemsetAsync(smax, 0, zbytes, stream);
      for (int c = 0; c < nchunk; ++c) {
        long long e0 = (long long)c * chunkE;
        long long e1 = e0 + chunkE < E ? e0 + chunkE : E;
        int blocks = (int)((e1 - e0 + 63) / 64);
        gemm_e<1><<<blocks, 256, 0, stream>>>(edgef, wf1, hW1, h, src, dst,
                                              nullptr, mbuf, score, smax, e0, e1);
      }
      for (int c = 0; c < nchunk; ++c) {
        long long e0 = (long long)c * chunkE;
        long long e1 = e0 + chunkE < E ? e0 + chunkE : E;
        int blocks = (int)((e1 - e0 + 63) / 64);
        if (nchunk > 1)
          gemm_e<0><<<blocks, 256, 0, stream>>>(edgef, wf1, hW1, h, src, dst,
                                                nullptr, mbuf, score, nullptr, e0, e1);
        edge_accum<<<2048, 256, 0, stream>>>(mbuf, score, smax, dst,
                                             denom, wsum, e0, e1);
      }
      finalize_k<<<finB, 256, 0, stream>>>(y2, y3, wsum, denom, hout, N);
    }
  }
}